// Round 17
// baseline (892.536 us; speedup 1.0000x reference)
//
#include <hip/hip_runtime.h>
#include <stdint.h>

#define NVOX 500000
#define NPAD 500224            // nbrT row padding (covers 3907*128)
#define ZERO_OFF (NVOX * 128)  // premultiplied element offset of the zero row

typedef float  f32x4  __attribute__((ext_vector_type(4)));
typedef short  short8 __attribute__((ext_vector_type(8)));

__device__ __forceinline__ short f2bf(float x){
  unsigned u = __float_as_uint(x);
  unsigned r = (u + 0x7fffu + ((u >> 16) & 1u)) >> 16;   // RNE truncate to bf16
  return (short)r;
}

__device__ __forceinline__ int cvt_pk_bf16(float lo, float hi){
  int r;
  asm("v_cvt_pk_bf16_f32 %0, %1, %2" : "=v"(r) : "v"(lo), "v"(hi));
  return r;  // bf16(lo) in [15:0], bf16(hi) in [31:16]
}

__device__ __forceinline__ void gload_lds16(const void* g, void* l){
  __builtin_amdgcn_global_load_lds(
      (const __attribute__((address_space(1))) unsigned int*)(uintptr_t)g,
      (__attribute__((address_space(3))) unsigned int*)(unsigned int)(uintptr_t)l,
      16, 0, 0);
}

// ---------------- prep: feats fp32 -> bf16 table ----------------
__global__ void cast_feats_kernel(const float* __restrict__ f, short* __restrict__ t){
  long i = ((long)blockIdx.x * 256 + threadIdx.x) * 8;   // 64e6 elems, exact grid
  float4 a = *(const float4*)(f + i);
  float4 b = *(const float4*)(f + i + 4);
  short8 o = { f2bf(a.x), f2bf(a.y), f2bf(a.z), f2bf(a.w),
               f2bf(b.x), f2bf(b.y), f2bf(b.z), f2bf(b.w) };
  *(short8*)(t + i) = o;
}

// ---------------- prep: transpose neighbor table ----------------
__global__ void prep_nbr_kernel(const int* __restrict__ nbr, int* __restrict__ nbrT){
  __shared__ int lds_n[6912];              // 256 rows x 27
  const int tid = threadIdx.x;
  const long base = (long)blockIdx.x * 6912;
  #pragma unroll
  for (int i = 0; i < 27; i++){
    long g = base + i*256 + tid;
    lds_n[i*256 + tid] = (g < (long)NVOX*27) ? nbr[g] : -1;
  }
  __syncthreads();
  const int row = blockIdx.x * 256 + tid;
  #pragma unroll
  for (int k = 0; k < 27; k++){
    int id = lds_n[tid*27 + k];
    nbrT[(size_t)k*NPAD + row] = (id < 0 ? NVOX : id) * 128;
  }
}

// ---------------- prep: weights -> bf16, MFMA-B fragment order ----------------
// layouts: cw_sw[phase54][nf*2+kslow:16][lane64][8]  (phase = k*2 + K-half; 16KB each)
//          w1_sw[nf32][ks4][lane][8]   (32-hid chunk c = 2 nf groups = contiguous 8KB)
//          w2_sw[ch32:16][nf8][lane][8] (chunk c covers K rows [c*32,c*32+32); 8KB each)
__global__ void prep_weights_kernel(const float* __restrict__ cw, const float* __restrict__ w1,
                                    const float* __restrict__ w2,
                                    short* __restrict__ cw_sw, short* __restrict__ w1_sw,
                                    short* __restrict__ w2_sw){
  int t = blockIdx.x * 256 + threadIdx.x;    // 71680 total, exact grid
  if (t < 55296){
    int k = t >> 11, rem = t & 2047;
    int nf = rem >> 8, ks = (rem >> 6) & 3, l = rem & 63;
    int g = l >> 4, c = l & 15;
    short8 o;
    #pragma unroll
    for (int j = 0; j < 8; j++){
      int kk = ks*32 + g*8 + j;
      o[j] = f2bf(cw[(k*128 + kk)*128 + nf*16 + c]);
    }
    size_t dst = (size_t)(k*2 + (ks >> 1))*8192 + (size_t)(nf*2 + (ks & 1))*512 + (size_t)l*8;
    *(short8*)(cw_sw + dst) = o;
  } else if (t < 63488){
    int u = t - 55296;
    int nf = u >> 8, ks = (u >> 6) & 3, l = u & 63;
    int g = l >> 4, c = l & 15;
    short8 o;
    #pragma unroll
    for (int j = 0; j < 8; j++){
      int kk = ks*32 + g*8 + j;
      o[j] = f2bf(w1[kk*512 + nf*16 + c]);   // w1 [128][512]
    }
    *(short8*)(w1_sw + (size_t)u*8) = o;
  } else {
    int u = t - 63488;                        // [0, 8192)
    int c32 = u >> 9, nf = (u >> 6) & 7, l = u & 63;
    int g = l >> 4, c = l & 15;
    short8 o;
    #pragma unroll
    for (int j = 0; j < 8; j++){
      int k = c32*32 + g*8 + j;
      o[j] = f2bf(w2[k*128 + nf*16 + c]);    // w2 [512][128]
    }
    *(short8*)(w2_sw + (size_t)u*8) = o;
  }
}

// ---------------- FUSED: sparse conv + LN + MLP + residual, one kernel ----------------
// Per 128-row block: conv v4 phases -> wave-local LN -> hn to wave-private LDS
// slice (XOR-swizzled) -> hn B-frags to regs -> mlp v6 chunks. hn16 global
// round-trip GONE. acc AGPRs reused for acc2. 3 waves/SIMD.
// LDS layout (shorts): conv: buf0=[0,8192), buf1=[8192,16384);
//                      hn:   wave wv slice = [wv*4096, wv*4096+4096);
//                      mlp:  buf b = [b*8192, b*8192+8192), w1c first 4096, w2c next 4096.
__global__ __launch_bounds__(256, 3)
void fused_kernel(const short* __restrict__ table, const int* __restrict__ nbrT,
                  const short* __restrict__ cw_sw,
                  const float* __restrict__ conv_b, const float* __restrict__ ln_g,
                  const float* __restrict__ ln_b,
                  const short* __restrict__ w1_sw, const short* __restrict__ w2_sw,
                  const float* __restrict__ b1, const float* __restrict__ b2,
                  const float* __restrict__ feats, float* __restrict__ out){
  __shared__ __align__(16) short lds[16384];   // 32KB
  const int tid = threadIdx.x;
  const int lane = tid & 63, wv = tid >> 6;
  const int l15 = lane & 15, lg = lane >> 4;
  const int rowbase = blockIdx.x * 128 + wv * 32;
  const int rowi = rowbase + l15;

  f32x4 acc[2][8];   // conv accumulator; re-zeroed and reused as mlp acc2
  #pragma unroll
  for (int m = 0; m < 2; m++)
    #pragma unroll
    for (int n = 0; n < 8; n++)
      acc[m][n] = f32x4{0.f, 0.f, 0.f, 0.f};

  // ================= conv phase (v4 structure) =================
  int idx_c[2], idx_n[2];
  #pragma unroll
  for (int m = 0; m < 2; m++) idx_c[m] = __builtin_nontemporal_load(&nbrT[rowi + m*16]);
  #pragma unroll
  for (int m = 0; m < 2; m++) idx_n[m] = __builtin_nontemporal_load(&nbrT[NPAD + rowi + m*16]);

  {
    const char* src = (const char*)cw_sw;
    char* dst = (char*)&lds[0];
    #pragma unroll
    for (int i = 0; i < 4; i++){ int off = i*4096 + tid*16; gload_lds16(src+off, dst+off); }
  }

  for (int k = 0; k < 27; k++){
    __syncthreads();
    {
      const char* src = (const char*)cw_sw + (size_t)(k*2 + 1)*16384;
      char* dst = (char*)&lds[8192];
      #pragma unroll
      for (int i = 0; i < 4; i++){ int off = i*4096 + tid*16; gload_lds16(src+off, dst+off); }
    }
    {
      short8 af0[2], af1[2];
      #pragma unroll
      for (int m = 0; m < 2; m++)
        af0[m] = *(const short8*)(table + (size_t)(unsigned)idx_c[m] + lg*8);
      #pragma unroll
      for (int m = 0; m < 2; m++)
        af1[m] = *(const short8*)(table + (size_t)(unsigned)idx_c[m] + 32 + lg*8);
      const short* b0 = &lds[0];
      #pragma unroll
      for (int n = 0; n < 8; n++){
        short8 b = *(const short8*)(b0 + ((n*2 + 0)*64 + lane)*8);
        #pragma unroll
        for (int m = 0; m < 2; m++)
          acc[m][n] = __builtin_amdgcn_mfma_f32_16x16x32_bf16(af0[m], b, acc[m][n], 0, 0, 0);
      }
      #pragma unroll
      for (int n = 0; n < 8; n++){
        short8 b = *(const short8*)(b0 + ((n*2 + 1)*64 + lane)*8);
        #pragma unroll
        for (int m = 0; m < 2; m++)
          acc[m][n] = __builtin_amdgcn_mfma_f32_16x16x32_bf16(af1[m], b, acc[m][n], 0, 0, 0);
      }
    }
    __syncthreads();
    if (k + 1 < 27){
      const char* src = (const char*)cw_sw + (size_t)(k+1)*32768;
      char* dst = (char*)&lds[0];
      #pragma unroll
      for (int i = 0; i < 4; i++){ int off = i*4096 + tid*16; gload_lds16(src+off, dst+off); }
    }
    int idx_n2[2];
    #pragma unroll
    for (int m = 0; m < 2; m++)
      idx_n2[m] = (k + 2 < 27) ? __builtin_nontemporal_load(&nbrT[(size_t)(k+2)*NPAD + rowi + m*16])
                               : ZERO_OFF;
    {
      short8 af2[2], af3[2];
      #pragma unroll
      for (int m = 0; m < 2; m++)
        af2[m] = *(const short8*)(table + (size_t)(unsigned)idx_c[m] + 64 + lg*8);
      #pragma unroll
      for (int m = 0; m < 2; m++)
        af3[m] = *(const short8*)(table + (size_t)(unsigned)idx_c[m] + 96 + lg*8);
      const short* b1p = &lds[8192];
      #pragma unroll
      for (int n = 0; n < 8; n++){
        short8 b = *(const short8*)(b1p + ((n*2 + 0)*64 + lane)*8);
        #pragma unroll
        for (int m = 0; m < 2; m++)
          acc[m][n] = __builtin_amdgcn_mfma_f32_16x16x32_bf16(af2[m], b, acc[m][n], 0, 0, 0);
      }
      #pragma unroll
      for (int n = 0; n < 8; n++){
        short8 b = *(const short8*)(b1p + ((n*2 + 1)*64 + lane)*8);
        #pragma unroll
        for (int m = 0; m < 2; m++)
          acc[m][n] = __builtin_amdgcn_mfma_f32_16x16x32_bf16(af3[m], b, acc[m][n], 0, 0, 0);
      }
    }
    #pragma unroll
    for (int m = 0; m < 2; m++){ idx_c[m] = idx_n[m]; idx_n[m] = idx_n2[m]; }
  }

  // ================= LN -> hn into wave-private LDS slice =================
  __syncthreads();                       // all waves done reading conv stage bufs
  short* hnw = &lds[wv * 4096];          // 32 rows x 128 cols bf16, XOR-swizzled
  {
    float cb[8], g8[8], be[8];
    #pragma unroll
    for (int n = 0; n < 8; n++){
      cb[n] = conv_b[n*16 + l15];
      g8[n] = ln_g[n*16 + l15];
      be[n] = ln_b[n*16 + l15];
    }
    #pragma unroll
    for (int m = 0; m < 2; m++){
      #pragma unroll
      for (int r = 0; r < 4; r++){
        float s = 0.f, s2 = 0.f;
        #pragma unroll
        for (int n = 0; n < 8; n++){
          float h = acc[m][n][r] + cb[n];
          acc[m][n][r] = h;
          s += h; s2 += h*h;
        }
        #pragma unroll
        for (int msk = 1; msk < 16; msk <<= 1){
          s  += __shfl_xor(s,  msk);
          s2 += __shfl_xor(s2, msk);
        }
        float mu  = s  * 0.0078125f;
        float var = s2 * 0.0078125f - mu*mu;
        float rs  = rsqrtf(var + 1e-6f);
        int rowloc = m*16 + lg*4 + r;
        #pragma unroll
        for (int n = 0; n < 8; n++){
          float hv = (acc[m][n][r] - mu) * rs * g8[n] + be[n];
          hnw[(rowloc*128 + n*16 + l15) ^ ((rowloc & 7) << 3)] = f2bf(hv);
        }
      }
    }
  }

  // read hn B-frags (lane holds hn[vox=l15][k=ks*32+lg*8+j]) — in-wave lgkm ordering
  short8 a1[4][2];
  #pragma unroll
  for (int ks = 0; ks < 4; ks++)
    #pragma unroll
    for (int m = 0; m < 2; m++){
      int rowloc = m*16 + l15;
      a1[ks][m] = *(const short8*)(hnw + ((rowloc*128 + ks*32 + lg*8) ^ ((rowloc & 7) << 3)));
    }
  __syncthreads();                       // all waves extracted hn before staging overwrites

  // ================= mlp phase (v6) =================
  #pragma unroll
  for (int m = 0; m < 2; m++)            // acc reused as acc2
    #pragma unroll
    for (int n = 0; n < 8; n++)
      acc[m][n] = f32x4{0.f, 0.f, 0.f, 0.f};

  const int sl0 = l15 + 32*(lg & 1);     // shuffle src lanes (words 0,1)
  const int sl1 = sl0 + 16;              // words 2,3
  const bool hiHalf = (lg >> 1) != 0;

  { // stage chunk 0 -> buf 0: w1c bytes [0,8192), w2c bytes [8192,16384)
    const char* s1 = (const char*)w1_sw;
    const char* s2 = (const char*)w2_sw;
    char* dst = (char*)&lds[0];
    #pragma unroll
    for (int i = 0; i < 2; i++){ int off = i*4096 + tid*16; gload_lds16(s1+off, dst+off); }
    #pragma unroll
    for (int i = 0; i < 2; i++){ int off = i*4096 + tid*16; gload_lds16(s2+off, dst+8192+off); }
  }

  for (int ch = 0; ch < 16; ch++){
    const int buf = ch & 1;
    __syncthreads();
    if (ch + 1 < 16){
      const char* s1 = (const char*)w1_sw + (size_t)(ch+1)*8192;
      const char* s2 = (const char*)w2_sw + (size_t)(ch+1)*8192;
      char* dst = (char*)&lds[(buf ^ 1) * 8192];   // 16KB buffers (short idx * 2 = bytes)
      #pragma unroll
      for (int i = 0; i < 2; i++){ int off = i*4096 + tid*16; gload_lds16(s1+off, dst+off); }
      #pragma unroll
      for (int i = 0; i < 2; i++){ int off = i*4096 + tid*16; gload_lds16(s2+off, dst+8192+off); }
    }
    const short* w1c = &lds[buf * 8192];
    const short* w2c = w1c + 4096;

    float4 b1v0 = *(const float4*)(b1 + ch*32 +  0 + lg*4);
    float4 b1v1 = *(const float4*)(b1 + ch*32 + 16 + lg*4);

    f32x4 p00 = f32x4{0.f,0.f,0.f,0.f}, p01 = f32x4{0.f,0.f,0.f,0.f};
    f32x4 p10 = f32x4{0.f,0.f,0.f,0.f}, p11 = f32x4{0.f,0.f,0.f,0.f};
    #pragma unroll
    for (int ks = 0; ks < 4; ks++){
      short8 wA0 = *(const short8*)(w1c + ((0*4 + ks)*64 + lane)*8);
      short8 wA1 = *(const short8*)(w1c + ((1*4 + ks)*64 + lane)*8);
      p00 = __builtin_amdgcn_mfma_f32_16x16x32_bf16(wA0, a1[ks][0], p00, 0, 0, 0);
      p01 = __builtin_amdgcn_mfma_f32_16x16x32_bf16(wA0, a1[ks][1], p01, 0, 0, 0);
      p10 = __builtin_amdgcn_mfma_f32_16x16x32_bf16(wA1, a1[ks][0], p10, 0, 0, 0);
      p11 = __builtin_amdgcn_mfma_f32_16x16x32_bf16(wA1, a1[ks][1], p11, 0, 0, 0);
    }

    int pk00[2], pk01[2], pk10[2], pk11[2];
    {
      float s0, s1v, s2v, s3;
      #define SILU4(P, BV, PK)                                            \
        s0 = (P)[0] + (BV).x; s0 = s0 / (1.f + __expf(-s0));              \
        s1v = (P)[1] + (BV).y; s1v = s1v / (1.f + __expf(-s1v));          \
        s2v = (P)[2] + (BV).z; s2v = s2v / (1.f + __expf(-s2v));          \
        s3 = (P)[3] + (BV).w; s3 = s3 / (1.f + __expf(-s3));              \
        (PK)[0] = cvt_pk_bf16(s0, s1v); (PK)[1] = cvt_pk_bf16(s2v, s3);
      SILU4(p00, b1v0, pk00)
      SILU4(p01, b1v0, pk01)
      SILU4(p10, b1v1, pk10)
      SILU4(p11, b1v1, pk11)
      #undef SILU4
    }

    union { int i[4]; short8 s; } a2u0, a2u1;
    #pragma unroll
    for (int w = 0; w < 4; w++){
      int src = (w < 2) ? sl0 : sl1;
      int t0 = __shfl(pk00[w & 1], src);
      int t1 = __shfl(pk10[w & 1], src);
      a2u0.i[w] = hiHalf ? t1 : t0;
      int u0 = __shfl(pk01[w & 1], src);
      int u1 = __shfl(pk11[w & 1], src);
      a2u1.i[w] = hiHalf ? u1 : u0;
    }

    #pragma unroll
    for (int n = 0; n < 8; n++){
      short8 b = *(const short8*)(w2c + (n*64 + lane)*8);
      acc[0][n] = __builtin_amdgcn_mfma_f32_16x16x32_bf16(a2u0.s, b, acc[0][n], 0, 0, 0);
      acc[1][n] = __builtin_amdgcn_mfma_f32_16x16x32_bf16(a2u1.s, b, acc[1][n], 0, 0, 0);
    }
  }

  // epilogue: + b2 + residual feats (fp32), store fp32
  float bb2[8];
  #pragma unroll
  for (int n = 0; n < 8; n++) bb2[n] = b2[n*16 + l15];
  #pragma unroll
  for (int m = 0; m < 2; m++)
    #pragma unroll
    for (int n = 0; n < 8; n++)
      #pragma unroll
      for (int r = 0; r < 4; r++){
        int row = rowbase + m*16 + lg*4 + r;
        if (row < NVOX){
          size_t ci = (size_t)row*128 + n*16 + l15;
          out[ci] = acc[m][n][r] + bb2[n] + feats[ci];
        }
      }
}

// ---------------- fallback conv (phase-major cw layout), small-ws paths ----------------
template<bool TBL>
__global__ __launch_bounds__(256, 2)
void conv_ln_kernel(const short* __restrict__ table, const float* __restrict__ feats,
                    const int* __restrict__ nbr, const short* __restrict__ cw_sw,
                    const float* __restrict__ conv_b, const float* __restrict__ ln_g,
                    const float* __restrict__ ln_b, short* __restrict__ hn16){
  __shared__ __align__(16) short lds_b[2][16384];
  const int tid = threadIdx.x;
  const int lane = tid & 63, wv = tid >> 6;
  const int l15 = lane & 15, lg = lane >> 4;
  const int rowbase = blockIdx.x * 256 + wv * 64;

  f32x4 acc[4][8];
  #pragma unroll
  for (int m = 0; m < 4; m++)
    #pragma unroll
    for (int n = 0; n < 8; n++)
      acc[m][n] = f32x4{0.f, 0.f, 0.f, 0.f};

  {
    const char* src = (const char*)cw_sw;
    char* dst = (char*)&lds_b[0][0];
    #pragma unroll
    for (int i = 0; i < 8; i++){ int off = i*4096 + tid*16; gload_lds16(src+off, dst+off); }
  }

  for (int k = 0; k < 27; k++){
    const int buf = k & 1;
    __syncthreads();
    if (k + 1 < 27){
      const char* src = (const char*)cw_sw + (size_t)(k+1)*32768;
      char* dst = (char*)&lds_b[buf ^ 1][0];
      #pragma unroll
      for (int i = 0; i < 8; i++){ int off = i*4096 + tid*16; gload_lds16(src+off, dst+off); }
    }
    int idxr[4];
    #pragma unroll
    for (int m = 0; m < 4; m++){
      int row = rowbase + m*16 + l15;
      row = row < NVOX ? row : NVOX - 1;
      int id = nbr[row*27 + k];
      idxr[m] = TBL ? (id < 0 ? NVOX : id) : id;
    }
    const short* bbase = &lds_b[buf][0];
    #pragma unroll
    for (int ks = 0; ks < 4; ks++){
      short8 af[4];
      #pragma unroll
      for (int m = 0; m < 4; m++){
        if constexpr (TBL){
          af[m] = *(const short8*)(table + (size_t)idxr[m]*128 + ks*32 + lg*8);
        } else {
          if (idxr[m] < 0){
            af[m] = short8{0,0,0,0,0,0,0,0};
          } else {
            const float* p = feats + (size_t)idxr[m]*128 + ks*32 + lg*8;
            float4 x = *(const float4*)p;
            float4 y = *(const float4*)(p + 4);
            af[m] = short8{ f2bf(x.x), f2bf(x.y), f2bf(x.z), f2bf(x.w),
                            f2bf(y.x), f2bf(y.y), f2bf(y.z), f2bf(y.w) };
          }
        }
      }
      #pragma unroll
      for (int n = 0; n < 8; n++){
        short8 b = *(const short8*)(bbase + (ks >> 1)*8192 + (((n*2 + (ks & 1))*64) + lane)*8);
        #pragma unroll
        for (int m = 0; m < 4; m++)
          acc[m][n] = __builtin_amdgcn_mfma_f32_16x16x32_bf16(af[m], b, acc[m][n], 0, 0, 0);
      }
    }
  }

  float cb[8], g8[8], be[8];
  #pragma unroll
  for (int n = 0; n < 8; n++){
    cb[n] = conv_b[n*16 + l15];
    g8[n] = ln_g[n*16 + l15];
    be[n] = ln_b[n*16 + l15];
  }
  #pragma unroll
  for (int m = 0; m < 4; m++){
    #pragma unroll
    for (int r = 0; r < 4; r++){
      float s = 0.f, s2 = 0.f;
      #pragma unroll
      for (int n = 0; n < 8; n++){
        float h = acc[m][n][r] + cb[n];
        acc[m][n][r] = h;
        s += h; s2 += h*h;
      }
      #pragma unroll
      for (int msk = 1; msk < 16; msk <<= 1){
        s  += __shfl_xor(s,  msk);
        s2 += __shfl_xor(s2, msk);
      }
      float mu  = s  * 0.0078125f;
      float var = s2 * 0.0078125f - mu*mu;
      float rs  = rsqrtf(var + 1e-6f);
      int row = rowbase + m*16 + lg*4 + r;
      if (row < NVOX){
        #pragma unroll
        for (int n = 0; n < 8; n++){
          float hv = (acc[m][n][r] - mu) * rs * g8[n] + be[n];
          hn16[(size_t)row*128 + n*16 + l15] = f2bf(hv);
        }
      }
    }
  }
}

// ---------------- fallback MLP v6 (standalone), small-ws paths ----------------
__global__ __launch_bounds__(256, 3)
void mlp_kernel(const short* __restrict__ hn16, const float* __restrict__ feats,
                const short* __restrict__ w1_sw, const short* __restrict__ w2_sw,
                const float* __restrict__ b1, const float* __restrict__ b2,
                float* __restrict__ out){
  __shared__ __align__(16) short lds_w[2][8192];
  const int tid = threadIdx.x;
  const int lane = tid & 63, wv = tid >> 6;
  const int l15 = lane & 15, lg = lane >> 4;
  const int rowbase = blockIdx.x * 128 + wv * 32;
  const int sl0 = l15 + 32*(lg & 1);
  const int sl1 = sl0 + 16;
  const bool hiHalf = (lg >> 1) != 0;

  f32x4 acc2[2][8];
  #pragma unroll
  for (int m = 0; m < 2; m++)
    #pragma unroll
    for (int n = 0; n < 8; n++)
      acc2[m][n] = f32x4{0.f, 0.f, 0.f, 0.f};

  int rowg[2];
  #pragma unroll
  for (int m = 0; m < 2; m++){
    int row = rowbase + m*16 + l15;
    rowg[m] = row < NVOX ? row : NVOX - 1;
  }

  short8 a1[4][2];
  #pragma unroll
  for (int ks = 0; ks < 4; ks++)
    #pragma unroll
    for (int m = 0; m < 2; m++)
      a1[ks][m] = *(const short8*)(hn16 + (size_t)rowg[m]*128 + ks*32 + lg*8);

  {
    const char* s1 = (const char*)w1_sw;
    const char* s2 = (const char*)w2_sw;
    char* dst = (char*)&lds_w[0][0];
    #pragma unroll
    for (int i = 0; i < 2; i++){ int off = i*4096 + tid*16; gload_lds16(s1+off, dst+off); }
    #pragma unroll
    for (int i = 0; i < 2; i++){ int off = i*4096 + tid*16; gload_lds16(s2+off, dst+8192+off); }
  }

  for (int ch = 0; ch < 16; ch++){
    const int buf = ch & 1;
    __syncthreads();
    if (ch + 1 < 16){
      const char* s1 = (const char*)w1_sw + (size_t)(ch+1)*8192;
      const char* s2 = (const char*)w2_sw + (size_t)(ch+1)*8192;
      char* dst = (char*)&lds_w[buf ^ 1][0];
      #pragma unroll
      for (int i = 0; i < 2; i++){ int off = i*4096 + tid*16; gload_lds16(s1+off, dst+off); }
      #pragma unroll
      for (int i = 0; i < 2; i++){ int off = i*4096 + tid*16; gload_lds16(s2+off, dst+8192+off); }
    }
    const short* w1c = &lds_w[buf][0];
    const short* w2c = &lds_w[buf][4096];

    float4 b1v0 = *(const float4*)(b1 + ch*32 +  0 + lg*4);
    float4 b1v1 = *(const float4*)(b1 + ch*32 + 16 + lg*4);

    f32x4 p00 = f32x4{0.f,0.f,0.f,0.f}, p01 = f32x4{0.f,0.f,0.f,0.f};
    f32x4 p10 = f32x4{0.f,0.f,0.f,0.f}, p11 = f32x4{0.f,0.f,0.f,0.f};
    #pragma unroll
    for (int ks = 0; ks < 4; ks++){
      short8 wA0 = *(const short8*)(w1c + ((0*4 + ks)*64 + lane)*8);
      short8 wA1 = *(const short8*)(w1c + ((1*4 + ks)*64 + lane)*8);
      p00 = __builtin_amdgcn_mfma_f32_16x16x32_bf16(wA0, a1[ks][0], p00, 0, 0, 0);
      p01 = __builtin_amdgcn_mfma_f32_16x16x32_bf16(wA0, a1[ks][1], p01, 0, 0, 0);
      p10 = __builtin_amdgcn_mfma_f32_16x16x32_bf16(wA1, a1[ks][0], p10, 0, 0, 0);
      p11 = __builtin_amdgcn_mfma_f32_16x16x32_bf16(wA1, a1[ks][1], p11, 0, 0, 0);
    }

    int pk00[2], pk01[2], pk10[2], pk11[2];
    {
      float s0, s1v, s2v, s3;
      #define SILU4(P, BV, PK)                                            \
        s0 = (P)[0] + (BV).x; s0 = s0 / (1.f + __expf(-s0));              \
        s1v = (P)[1] + (BV).y; s1v = s1v / (1.f + __expf(-s1v));          \
        s2v = (P)[2] + (BV).z; s2v = s2v / (1.f + __expf(-s2v));          \
        s3 = (P)[3] + (BV).w; s3 = s3 / (1.f + __expf(-s3));              \
        (PK)[0] = cvt_pk_bf16(s0, s1v); (PK)[1] = cvt_pk_bf16(s2v, s3);
      SILU4(p00, b1v0, pk00)
      SILU4(p01, b1v0, pk01)
      SILU4(p10, b1v1, pk10)
      SILU4(p11, b1v1, pk11)
      #undef SILU4
    }

    union { int i[4]; short8 s; } a2u0, a2u1;
    #pragma unroll
    for (int w = 0; w < 4; w++){
      int src = (w < 2) ? sl0 : sl1;
      int t0 = __shfl(pk00[w & 1], src);
      int t1 = __shfl(pk10[w & 1], src);
      a2u0.i[w] = hiHalf ? t1 : t0;
      int u0 = __shfl(pk01[w & 1], src);
      int u1 = __shfl(pk11[w & 1], src);
      a2u1.i[w] = hiHalf ? u1 : u0;
    }

    #pragma unroll
    for (int n = 0; n < 8; n++){
      short8 b = *(const short8*)(w2c + (n*64 + lane)*8);
      acc2[0][n] = __builtin_amdgcn_mfma_f32_16x16x32_bf16(a2u0.s, b, acc2[0][n], 0, 0, 0);
      acc2[1][n] = __builtin_amdgcn_mfma_f32_16x16x32_bf16(a2u1.s, b, acc2[1][n], 0, 0, 0);
    }
  }

  float bb2[8];
  #pragma unroll
  for (int n = 0; n < 8; n++) bb2[n] = b2[n*16 + l15];
  #pragma unroll
  for (int m = 0; m < 2; m++)
    #pragma unroll
    for (int n = 0; n < 8; n++)
      #pragma unroll
      for (int r = 0; r < 4; r++){
        int row = rowbase + m*16 + lg*4 + r;
        if (row < NVOX){
          size_t ci = (size_t)row*128 + n*16 + l15;
          out[ci] = acc2[m][n][r] + bb2[n] + feats[ci];
        }
      }
}

extern "C" void kernel_launch(void* const* d_in, const int* in_sizes, int n_in,
                              void* d_out, int out_size, void* d_ws, size_t ws_size,
                              hipStream_t stream){
  const float* feats = (const float*)d_in[0];
  const int*   nbr   = (const int*)  d_in[1];
  const float* cw    = (const float*)d_in[2];
  const float* cb    = (const float*)d_in[3];
  const float* lng   = (const float*)d_in[4];
  const float* lnb   = (const float*)d_in[5];
  const float* w1    = (const float*)d_in[6];
  const float* b1    = (const float*)d_in[7];
  const float* w2    = (const float*)d_in[8];
  const float* b2    = (const float*)d_in[9];
  float* out = (float*)d_out;

  char* ws = (char*)d_ws;
  const size_t TABLE_B = (size_t)(NVOX + 1) * 256;   // 128,000,256
  const size_t HN_B    = (size_t)NVOX * 256;         // 128,000,000
  const size_t CW_B    = 55296u * 16u;               // 884,736
  const size_t W1_B    = 8192u * 16u;                // 131,072
  const size_t W2_B    = 8192u * 16u;
  const size_t NBRT_B  = (size_t)27 * NPAD * 4;      // 54,024,192
  const size_t need_fused = TABLE_B + CW_B + W1_B + W2_B + NBRT_B;  // ~183 MB
  const size_t need_full  = TABLE_B + HN_B + CW_B + W1_B + W2_B;

  if (ws_size >= need_fused){
    short* table = (short*)ws;
    short* cw_sw = (short*)(ws + TABLE_B);
    short* w1_sw = (short*)(ws + TABLE_B + CW_B);
    short* w2_sw = (short*)(ws + TABLE_B + CW_B + W1_B);
    int*   nbrT  = (int*)  (ws + TABLE_B + CW_B + W1_B + W2_B);

    cast_feats_kernel<<<31250, 256, 0, stream>>>(feats, table);
    hipMemsetAsync((void*)(table + (size_t)NVOX * 128), 0, 256, stream);  // zero row
    prep_nbr_kernel<<<1954, 256, 0, stream>>>(nbr, nbrT);
    prep_weights_kernel<<<280, 256, 0, stream>>>(cw, w1, w2, cw_sw, w1_sw, w2_sw);
    fused_kernel<<<3907, 256, 0, stream>>>(table, nbrT, cw_sw, cb, lng, lnb,
                                           w1_sw, w2_sw, b1, b2, feats, out);
  } else if (ws_size >= need_full){
    short* table = (short*)ws;
    short* hn16  = (short*)(ws + TABLE_B);
    short* cw_sw = (short*)(ws + TABLE_B + HN_B);
    short* w1_sw = (short*)(ws + TABLE_B + HN_B + CW_B);
    short* w2_sw = (short*)(ws + TABLE_B + HN_B + CW_B + W1_B);

    cast_feats_kernel<<<31250, 256, 0, stream>>>(feats, table);
    hipMemsetAsync((void*)(table + (size_t)NVOX * 128), 0, 256, stream);
    prep_weights_kernel<<<280, 256, 0, stream>>>(cw, w1, w2, cw_sw, w1_sw, w2_sw);
    conv_ln_kernel<true><<<1954, 256, 0, stream>>>(table, feats, nbr, cw_sw, cb, lng, lnb, hn16);
    mlp_kernel<<<3907, 256, 0, stream>>>(hn16, feats, w1_sw, w2_sw, b1, b2, out);
  } else {
    short* hn16  = (short*)ws;
    short* cw_sw = (short*)(ws + HN_B);
    short* w1_sw = (short*)(ws + HN_B + CW_B);
    short* w2_sw = (short*)(ws + HN_B + CW_B + W1_B);

    prep_weights_kernel<<<280, 256, 0, stream>>>(cw, w1, w2, cw_sw, w1_sw, w2_sw);
    conv_ln_kernel<false><<<1954, 256, 0, stream>>>(nullptr, feats, nbr, cw_sw, cb, lng, lnb, hn16);
    mlp_kernel<<<3907, 256, 0, stream>>>(hn16, feats, w1_sw, w2_sw, b1, b2, out);
  }
}

// Round 18
// 854.638 us; speedup vs baseline: 1.0443x; 1.0443x over previous
//
#include <hip/hip_runtime.h>
#include <stdint.h>

#define NVOX 500000
#define NPAD 500224            // nbrT row padding (1954*256; covers 3907*128)
#define ZERO_OFF (NVOX * 128)  // premultiplied element offset of the zero row

typedef float  f32x4  __attribute__((ext_vector_type(4)));
typedef short  short8 __attribute__((ext_vector_type(8)));

__device__ __forceinline__ short f2bf(float x){
  unsigned u = __float_as_uint(x);
  unsigned r = (u + 0x7fffu + ((u >> 16) & 1u)) >> 16;   // RNE truncate to bf16
  return (short)r;
}

__device__ __forceinline__ int cvt_pk_bf16(float lo, float hi){
  int r;
  asm("v_cvt_pk_bf16_f32 %0, %1, %2" : "=v"(r) : "v"(lo), "v"(hi));
  return r;  // bf16(lo) in [15:0], bf16(hi) in [31:16]
}

__device__ __forceinline__ void gload_lds16(const void* g, void* l){
  __builtin_amdgcn_global_load_lds(
      (const __attribute__((address_space(1))) unsigned int*)(uintptr_t)g,
      (__attribute__((address_space(3))) unsigned int*)(unsigned int)(uintptr_t)l,
      16, 0, 0);
}

// ---------------- prep: feats fp32 -> bf16 table ----------------
__global__ void cast_feats_kernel(const float* __restrict__ f, short* __restrict__ t){
  long i = ((long)blockIdx.x * 256 + threadIdx.x) * 8;   // 64e6 elems, exact grid
  float4 a = *(const float4*)(f + i);
  float4 b = *(const float4*)(f + i + 4);
  short8 o = { f2bf(a.x), f2bf(a.y), f2bf(a.z), f2bf(a.w),
               f2bf(b.x), f2bf(b.y), f2bf(b.z), f2bf(b.w) };
  *(short8*)(t + i) = o;
}

// ---------------- prep: transpose neighbor table ----------------
__global__ void prep_nbr_kernel(const int* __restrict__ nbr, int* __restrict__ nbrT){
  __shared__ int lds_n[6912];              // 256 rows x 27
  const int tid = threadIdx.x;
  const long base = (long)blockIdx.x * 6912;
  #pragma unroll
  for (int i = 0; i < 27; i++){
    long g = base + i*256 + tid;
    lds_n[i*256 + tid] = (g < (long)NVOX*27) ? nbr[g] : -1;
  }
  __syncthreads();
  const int row = blockIdx.x * 256 + tid;
  #pragma unroll
  for (int k = 0; k < 27; k++){
    int id = lds_n[tid*27 + k];
    nbrT[(size_t)k*NPAD + row] = (id < 0 ? NVOX : id) * 128;
  }
}

// ---------------- prep: weights -> bf16, MFMA-B fragment order ----------------
// B-frag (16x16x32): lane l holds B[k = ks*32 + (l>>4)*8 + j][col = nf*16 + (l&15)]
// layouts: cw_sw[phase54][nf*2+kslow:16][lane64][8]  (phase = k*2 + K-half; 16KB each)
//          w1_sw[nf32][ks4][lane][8]   (32-hid chunk c = 2 nf groups = contiguous 8KB)
//          w2_sw[ch32:16][nf8][lane][8] (chunk c covers K rows [c*32,c*32+32); 8KB each)
__global__ void prep_weights_kernel(const float* __restrict__ cw, const float* __restrict__ w1,
                                    const float* __restrict__ w2,
                                    short* __restrict__ cw_sw, short* __restrict__ w1_sw,
                                    short* __restrict__ w2_sw){
  int t = blockIdx.x * 256 + threadIdx.x;    // 71680 total, exact grid
  if (t < 55296){
    int k = t >> 11, rem = t & 2047;
    int nf = rem >> 8, ks = (rem >> 6) & 3, l = rem & 63;
    int g = l >> 4, c = l & 15;
    short8 o;
    #pragma unroll
    for (int j = 0; j < 8; j++){
      int kk = ks*32 + g*8 + j;
      o[j] = f2bf(cw[(k*128 + kk)*128 + nf*16 + c]);
    }
    size_t dst = (size_t)(k*2 + (ks >> 1))*8192 + (size_t)(nf*2 + (ks & 1))*512 + (size_t)l*8;
    *(short8*)(cw_sw + dst) = o;
  } else if (t < 63488){
    int u = t - 55296;
    int nf = u >> 8, ks = (u >> 6) & 3, l = u & 63;
    int g = l >> 4, c = l & 15;
    short8 o;
    #pragma unroll
    for (int j = 0; j < 8; j++){
      int kk = ks*32 + g*8 + j;
      o[j] = f2bf(w1[kk*512 + nf*16 + c]);   // w1 [128][512]
    }
    *(short8*)(w1_sw + (size_t)u*8) = o;
  } else {
    int u = t - 63488;                        // [0, 8192)
    int c32 = u >> 9, nf = (u >> 6) & 7, l = u & 63;
    int g = l >> 4, c = l & 15;
    short8 o;
    #pragma unroll
    for (int j = 0; j < 8; j++){
      int k = c32*32 + g*8 + j;
      o[j] = f2bf(w2[k*128 + nf*16 + c]);    // w2 [512][128]
    }
    *(short8*)(w2_sw + (size_t)u*8) = o;
  }
}

// ---------------- fused sparse conv + LN v4 (best: 4 blocks/CU) + nt stream hints ----------------
__global__ __launch_bounds__(256, 4)
void conv_ln_v4_kernel(const short* __restrict__ table, const int* __restrict__ nbrT,
                       const short* __restrict__ cw_sw,
                       const float* __restrict__ conv_b, const float* __restrict__ ln_g,
                       const float* __restrict__ ln_b, short* __restrict__ hn16){
  __shared__ __align__(16) short lds_b[2][8192];   // 2 x 16KB K-half B stages
  const int tid = threadIdx.x;
  const int lane = tid & 63, wv = tid >> 6;
  const int l15 = lane & 15, lg = lane >> 4;
  const int rowbase = blockIdx.x * 128 + wv * 32;
  const int rowi = rowbase + l15;

  f32x4 acc[2][8];
  #pragma unroll
  for (int m = 0; m < 2; m++)
    #pragma unroll
    for (int n = 0; n < 8; n++)
      acc[m][n] = f32x4{0.f, 0.f, 0.f, 0.f};

  int idx_c[2], idx_n[2];
  #pragma unroll
  for (int m = 0; m < 2; m++) idx_c[m] = __builtin_nontemporal_load(&nbrT[rowi + m*16]);
  #pragma unroll
  for (int m = 0; m < 2; m++) idx_n[m] = __builtin_nontemporal_load(&nbrT[NPAD + rowi + m*16]);

  {
    const char* src = (const char*)cw_sw;
    char* dst = (char*)&lds_b[0][0];
    #pragma unroll
    for (int i = 0; i < 4; i++){ int off = i*4096 + tid*16; gload_lds16(src+off, dst+off); }
  }

  for (int k = 0; k < 27; k++){
    __syncthreads();
    {
      const char* src = (const char*)cw_sw + (size_t)(k*2 + 1)*16384;
      char* dst = (char*)&lds_b[1][0];
      #pragma unroll
      for (int i = 0; i < 4; i++){ int off = i*4096 + tid*16; gload_lds16(src+off, dst+off); }
    }
    {
      short8 af0[2], af1[2];
      #pragma unroll
      for (int m = 0; m < 2; m++)
        af0[m] = *(const short8*)(table + (size_t)(unsigned)idx_c[m] + lg*8);
      #pragma unroll
      for (int m = 0; m < 2; m++)
        af1[m] = *(const short8*)(table + (size_t)(unsigned)idx_c[m] + 32 + lg*8);
      const short* b0 = &lds_b[0][0];
      #pragma unroll
      for (int n = 0; n < 8; n++){
        short8 b = *(const short8*)(b0 + ((n*2 + 0)*64 + lane)*8);
        #pragma unroll
        for (int m = 0; m < 2; m++)
          acc[m][n] = __builtin_amdgcn_mfma_f32_16x16x32_bf16(af0[m], b, acc[m][n], 0, 0, 0);
      }
      #pragma unroll
      for (int n = 0; n < 8; n++){
        short8 b = *(const short8*)(b0 + ((n*2 + 1)*64 + lane)*8);
        #pragma unroll
        for (int m = 0; m < 2; m++)
          acc[m][n] = __builtin_amdgcn_mfma_f32_16x16x32_bf16(af1[m], b, acc[m][n], 0, 0, 0);
      }
    }
    __syncthreads();
    if (k + 1 < 27){
      const char* src = (const char*)cw_sw + (size_t)(k+1)*32768;
      char* dst = (char*)&lds_b[0][0];
      #pragma unroll
      for (int i = 0; i < 4; i++){ int off = i*4096 + tid*16; gload_lds16(src+off, dst+off); }
    }
    int idx_n2[2];
    #pragma unroll
    for (int m = 0; m < 2; m++)
      idx_n2[m] = (k + 2 < 27) ? __builtin_nontemporal_load(&nbrT[(size_t)(k+2)*NPAD + rowi + m*16])
                               : ZERO_OFF;
    {
      short8 af2[2], af3[2];
      #pragma unroll
      for (int m = 0; m < 2; m++)
        af2[m] = *(const short8*)(table + (size_t)(unsigned)idx_c[m] + 64 + lg*8);
      #pragma unroll
      for (int m = 0; m < 2; m++)
        af3[m] = *(const short8*)(table + (size_t)(unsigned)idx_c[m] + 96 + lg*8);
      const short* b1 = &lds_b[1][0];
      #pragma unroll
      for (int n = 0; n < 8; n++){
        short8 b = *(const short8*)(b1 + ((n*2 + 0)*64 + lane)*8);
        #pragma unroll
        for (int m = 0; m < 2; m++)
          acc[m][n] = __builtin_amdgcn_mfma_f32_16x16x32_bf16(af2[m], b, acc[m][n], 0, 0, 0);
      }
      #pragma unroll
      for (int n = 0; n < 8; n++){
        short8 b = *(const short8*)(b1 + ((n*2 + 1)*64 + lane)*8);
        #pragma unroll
        for (int m = 0; m < 2; m++)
          acc[m][n] = __builtin_amdgcn_mfma_f32_16x16x32_bf16(af3[m], b, acc[m][n], 0, 0, 0);
      }
    }
    #pragma unroll
    for (int m = 0; m < 2; m++){ idx_c[m] = idx_n[m]; idx_n[m] = idx_n2[m]; }
  }

  // epilogue: +conv_b, wave-local LayerNorm (fp32), -> bf16 (nt stores)
  float cb[8], g8[8], be[8];
  #pragma unroll
  for (int n = 0; n < 8; n++){
    cb[n] = conv_b[n*16 + l15];
    g8[n] = ln_g[n*16 + l15];
    be[n] = ln_b[n*16 + l15];
  }
  #pragma unroll
  for (int m = 0; m < 2; m++){
    #pragma unroll
    for (int r = 0; r < 4; r++){
      float s = 0.f, s2 = 0.f;
      #pragma unroll
      for (int n = 0; n < 8; n++){
        float h = acc[m][n][r] + cb[n];
        acc[m][n][r] = h;
        s += h; s2 += h*h;
      }
      #pragma unroll
      for (int msk = 1; msk < 16; msk <<= 1){
        s  += __shfl_xor(s,  msk);
        s2 += __shfl_xor(s2, msk);
      }
      float mu  = s  * 0.0078125f;
      float var = s2 * 0.0078125f - mu*mu;
      float rs  = rsqrtf(var + 1e-6f);
      int row = rowbase + m*16 + lg*4 + r;
      if (row < NVOX){
        #pragma unroll
        for (int n = 0; n < 8; n++){
          float hv = (acc[m][n][r] - mu) * rs * g8[n] + be[n];
          __builtin_nontemporal_store(f2bf(hv), &hn16[(size_t)row*128 + n*16 + l15]);
        }
      }
    }
  }
}

// ---------------- fallback conv (phase-major cw layout), small-ws paths ----------------
template<bool TBL>
__global__ __launch_bounds__(256, 2)
void conv_ln_kernel(const short* __restrict__ table, const float* __restrict__ feats,
                    const int* __restrict__ nbr, const short* __restrict__ cw_sw,
                    const float* __restrict__ conv_b, const float* __restrict__ ln_g,
                    const float* __restrict__ ln_b, short* __restrict__ hn16){
  __shared__ __align__(16) short lds_b[2][16384];
  const int tid = threadIdx.x;
  const int lane = tid & 63, wv = tid >> 6;
  const int l15 = lane & 15, lg = lane >> 4;
  const int rowbase = blockIdx.x * 256 + wv * 64;

  f32x4 acc[4][8];
  #pragma unroll
  for (int m = 0; m < 4; m++)
    #pragma unroll
    for (int n = 0; n < 8; n++)
      acc[m][n] = f32x4{0.f, 0.f, 0.f, 0.f};

  {
    const char* src = (const char*)cw_sw;
    char* dst = (char*)&lds_b[0][0];
    #pragma unroll
    for (int i = 0; i < 8; i++){ int off = i*4096 + tid*16; gload_lds16(src+off, dst+off); }
  }

  for (int k = 0; k < 27; k++){
    const int buf = k & 1;
    __syncthreads();
    if (k + 1 < 27){
      const char* src = (const char*)cw_sw + (size_t)(k+1)*32768;
      char* dst = (char*)&lds_b[buf ^ 1][0];
      #pragma unroll
      for (int i = 0; i < 8; i++){ int off = i*4096 + tid*16; gload_lds16(src+off, dst+off); }
    }
    int idxr[4];
    #pragma unroll
    for (int m = 0; m < 4; m++){
      int row = rowbase + m*16 + l15;
      row = row < NVOX ? row : NVOX - 1;
      int id = nbr[row*27 + k];
      idxr[m] = TBL ? (id < 0 ? NVOX : id) : id;
    }
    const short* bbase = &lds_b[buf][0];
    #pragma unroll
    for (int ks = 0; ks < 4; ks++){
      short8 af[4];
      #pragma unroll
      for (int m = 0; m < 4; m++){
        if constexpr (TBL){
          af[m] = *(const short8*)(table + (size_t)idxr[m]*128 + ks*32 + lg*8);
        } else {
          if (idxr[m] < 0){
            af[m] = short8{0,0,0,0,0,0,0,0};
          } else {
            const float* p = feats + (size_t)idxr[m]*128 + ks*32 + lg*8;
            float4 x = *(const float4*)p;
            float4 y = *(const float4*)(p + 4);
            af[m] = short8{ f2bf(x.x), f2bf(x.y), f2bf(x.z), f2bf(x.w),
                            f2bf(y.x), f2bf(y.y), f2bf(y.z), f2bf(y.w) };
          }
        }
      }
      #pragma unroll
      for (int n = 0; n < 8; n++){
        short8 b = *(const short8*)(bbase + (ks >> 1)*8192 + (((n*2 + (ks & 1))*64) + lane)*8);
        #pragma unroll
        for (int m = 0; m < 4; m++)
          acc[m][n] = __builtin_amdgcn_mfma_f32_16x16x32_bf16(af[m], b, acc[m][n], 0, 0, 0);
      }
    }
  }

  float cb[8], g8[8], be[8];
  #pragma unroll
  for (int n = 0; n < 8; n++){
    cb[n] = conv_b[n*16 + l15];
    g8[n] = ln_g[n*16 + l15];
    be[n] = ln_b[n*16 + l15];
  }
  #pragma unroll
  for (int m = 0; m < 4; m++){
    #pragma unroll
    for (int r = 0; r < 4; r++){
      float s = 0.f, s2 = 0.f;
      #pragma unroll
      for (int n = 0; n < 8; n++){
        float h = acc[m][n][r] + cb[n];
        acc[m][n][r] = h;
        s += h; s2 += h*h;
      }
      #pragma unroll
      for (int msk = 1; msk < 16; msk <<= 1){
        s  += __shfl_xor(s,  msk);
        s2 += __shfl_xor(s2, msk);
      }
      float mu  = s  * 0.0078125f;
      float var = s2 * 0.0078125f - mu*mu;
      float rs  = rsqrtf(var + 1e-6f);
      int row = rowbase + m*16 + lg*4 + r;
      if (row < NVOX){
        #pragma unroll
        for (int n = 0; n < 8; n++){
          float hv = (acc[m][n][r] - mu) * rs * g8[n] + be[n];
          hn16[(size_t)row*128 + n*16 + l15] = f2bf(hv);
        }
      }
    }
  }
}

// ---------------- fused MLP v6 (best): swapped-GEMM1 + in-register transpose ----------------
__global__ __launch_bounds__(256, 3)
void mlp_kernel(const short* __restrict__ hn16, const float* __restrict__ feats,
                const short* __restrict__ w1_sw, const short* __restrict__ w2_sw,
                const float* __restrict__ b1, const float* __restrict__ b2,
                float* __restrict__ out){
  __shared__ __align__(16) short lds_w[2][8192];    // 2 x (w1c 8KB | w2c 8KB)
  const int tid = threadIdx.x;
  const int lane = tid & 63, wv = tid >> 6;
  const int l15 = lane & 15, lg = lane >> 4;
  const int rowbase = blockIdx.x * 128 + wv * 32;
  const int sl0 = l15 + 32*(lg & 1);   // shuffle src lanes (words 0,1)
  const int sl1 = sl0 + 16;            // words 2,3
  const bool hiHalf = (lg >> 1) != 0;

  f32x4 acc2[2][8];
  #pragma unroll
  for (int m = 0; m < 2; m++)
    #pragma unroll
    for (int n = 0; n < 8; n++)
      acc2[m][n] = f32x4{0.f, 0.f, 0.f, 0.f};

  int rowg[2];
  #pragma unroll
  for (int m = 0; m < 2; m++){
    int row = rowbase + m*16 + l15;
    rowg[m] = row < NVOX ? row : NVOX - 1;
  }

  short8 a1[4][2];
  #pragma unroll
  for (int ks = 0; ks < 4; ks++)
    #pragma unroll
    for (int m = 0; m < 2; m++)
      a1[ks][m] = *(const short8*)(hn16 + (size_t)rowg[m]*128 + ks*32 + lg*8);

  {
    const char* s1 = (const char*)w1_sw;
    const char* s2 = (const char*)w2_sw;
    char* dst = (char*)&lds_w[0][0];
    #pragma unroll
    for (int i = 0; i < 2; i++){ int off = i*4096 + tid*16; gload_lds16(s1+off, dst+off); }
    #pragma unroll
    for (int i = 0; i < 2; i++){ int off = i*4096 + tid*16; gload_lds16(s2+off, dst+8192+off); }
  }

  for (int ch = 0; ch < 16; ch++){
    const int buf = ch & 1;
    __syncthreads();
    if (ch + 1 < 16){
      const char* s1 = (const char*)w1_sw + (size_t)(ch+1)*8192;
      const char* s2 = (const char*)w2_sw + (size_t)(ch+1)*8192;
      char* dst = (char*)&lds_w[buf ^ 1][0];
      #pragma unroll
      for (int i = 0; i < 2; i++){ int off = i*4096 + tid*16; gload_lds16(s1+off, dst+off); }
      #pragma unroll
      for (int i = 0; i < 2; i++){ int off = i*4096 + tid*16; gload_lds16(s2+off, dst+8192+off); }
    }
    const short* w1c = &lds_w[buf][0];
    const short* w2c = &lds_w[buf][4096];

    float4 b1v0 = *(const float4*)(b1 + ch*32 +  0 + lg*4);
    float4 b1v1 = *(const float4*)(b1 + ch*32 + 16 + lg*4);

    f32x4 p00 = f32x4{0.f,0.f,0.f,0.f}, p01 = f32x4{0.f,0.f,0.f,0.f};
    f32x4 p10 = f32x4{0.f,0.f,0.f,0.f}, p11 = f32x4{0.f,0.f,0.f,0.f};
    #pragma unroll
    for (int ks = 0; ks < 4; ks++){
      short8 wA0 = *(const short8*)(w1c + ((0*4 + ks)*64 + lane)*8);
      short8 wA1 = *(const short8*)(w1c + ((1*4 + ks)*64 + lane)*8);
      p00 = __builtin_amdgcn_mfma_f32_16x16x32_bf16(wA0, a1[ks][0], p00, 0, 0, 0);
      p01 = __builtin_amdgcn_mfma_f32_16x16x32_bf16(wA0, a1[ks][1], p01, 0, 0, 0);
      p10 = __builtin_amdgcn_mfma_f32_16x16x32_bf16(wA1, a1[ks][0], p10, 0, 0, 0);
      p11 = __builtin_amdgcn_mfma_f32_16x16x32_bf16(wA1, a1[ks][1], p11, 0, 0, 0);
    }

    int pk00[2], pk01[2], pk10[2], pk11[2];
    {
      float s0, s1v, s2v, s3;
      #define SILU4(P, BV, PK)                                            \
        s0 = (P)[0] + (BV).x; s0 = s0 / (1.f + __expf(-s0));              \
        s1v = (P)[1] + (BV).y; s1v = s1v / (1.f + __expf(-s1v));          \
        s2v = (P)[2] + (BV).z; s2v = s2v / (1.f + __expf(-s2v));          \
        s3 = (P)[3] + (BV).w; s3 = s3 / (1.f + __expf(-s3));              \
        (PK)[0] = cvt_pk_bf16(s0, s1v); (PK)[1] = cvt_pk_bf16(s2v, s3);
      SILU4(p00, b1v0, pk00)
      SILU4(p01, b1v0, pk01)
      SILU4(p10, b1v1, pk10)
      SILU4(p11, b1v1, pk11)
      #undef SILU4
    }

    union { int i[4]; short8 s; } a2u0, a2u1;
    #pragma unroll
    for (int w = 0; w < 4; w++){
      int src = (w < 2) ? sl0 : sl1;
      int t0 = __shfl(pk00[w & 1], src);
      int t1 = __shfl(pk10[w & 1], src);
      a2u0.i[w] = hiHalf ? t1 : t0;
      int u0 = __shfl(pk01[w & 1], src);
      int u1 = __shfl(pk11[w & 1], src);
      a2u1.i[w] = hiHalf ? u1 : u0;
    }

    #pragma unroll
    for (int n = 0; n < 8; n++){
      short8 b = *(const short8*)(w2c + (n*64 + lane)*8);
      acc2[0][n] = __builtin_amdgcn_mfma_f32_16x16x32_bf16(a2u0.s, b, acc2[0][n], 0, 0, 0);
      acc2[1][n] = __builtin_amdgcn_mfma_f32_16x16x32_bf16(a2u1.s, b, acc2[1][n], 0, 0, 0);
    }
  }

  float bb2[8];
  #pragma unroll
  for (int n = 0; n < 8; n++) bb2[n] = b2[n*16 + l15];
  #pragma unroll
  for (int m = 0; m < 2; m++)
    #pragma unroll
    for (int n = 0; n < 8; n++)
      #pragma unroll
      for (int r = 0; r < 4; r++){
        int row = rowbase + m*16 + lg*4 + r;
        if (row < NVOX){
          size_t ci = (size_t)row*128 + n*16 + l15;
          out[ci] = acc2[m][n][r] + bb2[n] + feats[ci];
        }
      }
}

extern "C" void kernel_launch(void* const* d_in, const int* in_sizes, int n_in,
                              void* d_out, int out_size, void* d_ws, size_t ws_size,
                              hipStream_t stream){
  const float* feats = (const float*)d_in[0];
  const int*   nbr   = (const int*)  d_in[1];
  const float* cw    = (const float*)d_in[2];
  const float* cb    = (const float*)d_in[3];
  const float* lng   = (const float*)d_in[4];
  const float* lnb   = (const float*)d_in[5];
  const float* w1    = (const float*)d_in[6];
  const float* b1    = (const float*)d_in[7];
  const float* w2    = (const float*)d_in[8];
  const float* b2    = (const float*)d_in[9];
  float* out = (float*)d_out;

  char* ws = (char*)d_ws;
  const size_t TABLE_B = (size_t)(NVOX + 1) * 256;   // 128,000,256
  const size_t HN_B    = (size_t)NVOX * 256;         // 128,000,000
  const size_t CW_B    = 55296u * 16u;               // 884,736
  const size_t W1_B    = 8192u * 16u;                // 131,072
  const size_t W2_B    = 8192u * 16u;
  const size_t NBRT_B  = (size_t)27 * NPAD * 4;      // 54,024,192
  const size_t need_full = TABLE_B + HN_B + CW_B + W1_B + W2_B;
  const size_t need_pf   = need_full + NBRT_B;

  if (ws_size >= need_pf){
    short* table = (short*)ws;
    short* hn16  = (short*)(ws + TABLE_B);
    short* cw_sw = (short*)(ws + TABLE_B + HN_B);
    short* w1_sw = (short*)(ws + TABLE_B + HN_B + CW_B);
    short* w2_sw = (short*)(ws + TABLE_B + HN_B + CW_B + W1_B);
    int*   nbrT  = (int*)  (ws + need_full);

    cast_feats_kernel<<<31250, 256, 0, stream>>>(feats, table);
    hipMemsetAsync((void*)(table + (size_t)NVOX * 128), 0, 256, stream);  // zero row
    prep_nbr_kernel<<<1954, 256, 0, stream>>>(nbr, nbrT);
    prep_weights_kernel<<<280, 256, 0, stream>>>(cw, w1, w2, cw_sw, w1_sw, w2_sw);
    conv_ln_v4_kernel<<<3907, 256, 0, stream>>>(table, nbrT, cw_sw, cb, lng, lnb, hn16);
    mlp_kernel<<<3907, 256, 0, stream>>>(hn16, feats, w1_sw, w2_sw, b1, b2, out);
  } else if (ws_size >= need_full){
    short* table = (short*)ws;
    short* hn16  = (short*)(ws + TABLE_B);
    short* cw_sw = (short*)(ws + TABLE_B + HN_B);
    short* w1_sw = (short*)(ws + TABLE_B + HN_B + CW_B);
    short* w2_sw = (short*)(ws + TABLE_B + HN_B + CW_B + W1_B);

    cast_feats_kernel<<<31250, 256, 0, stream>>>(feats, table);
    hipMemsetAsync((void*)(table + (size_t)NVOX * 128), 0, 256, stream);
    prep_weights_kernel<<<280, 256, 0, stream>>>(cw, w1, w2, cw_sw, w1_sw, w2_sw);
    conv_ln_kernel<true><<<1954, 256, 0, stream>>>(table, feats, nbr, cw_sw, cb, lng, lnb, hn16);
    mlp_kernel<<<3907, 256, 0, stream>>>(hn16, feats, w1_sw, w2_sw, b1, b2, out);
  } else {
    short* hn16  = (short*)ws;
    short* cw_sw = (short*)(ws + HN_B);
    short* w1_sw = (short*)(ws + HN_B + CW_B);
    short* w2_sw = (short*)(ws + HN_B + CW_B + W1_B);

    prep_weights_kernel<<<280, 256, 0, stream>>>(cw, w1, w2, cw_sw, w1_sw, w2_sw);
    conv_ln_kernel<false><<<1954, 256, 0, stream>>>(nullptr, feats, nbr, cw_sw, cb, lng, lnb, hn16);
    mlp_kernel<<<3907, 256, 0, stream>>>(hn16, feats, w1_sw, w2_sw, b1, b2, out);
  }
}